// Round 3
// baseline (411.134 us; speedup 1.0000x reference)
//
#include <hip/hip_runtime.h>

// ResNetBlock_MoE: B=64,C=64,H=W=56,E=8,TOPK=2. f32 in / f32 out.
// out = sum_k w_k*relu(bn2(conv2(relu(bn1(conv1(x,e)))))+x), plus dense_w.
//
// R14: barrier-free K-loop. R13 post-mortem: all pipes <20% busy at 93us —
// latency-bound with lockstep barriers (4 chunk barriers = vmcnt(0) drains +
// wave skew) and 1KB of LDS A-read per MFMA (18us/CU LDS pipe).
// Restructure: M-split blocks (grid.y=mt) need only 72KB of A -> staged ONCE,
// zero barriers in the 36-step loop; waves free-run. Wave = 1 expert x 32
// out-ch x 64 positions (2 B frags) -> each A ds_read feeds 2 MFMAs (A-LDS
// traffic halved). B prefetch: 2 streams x depth 4 = 8 outstanding (as R13).
// conv2 combines experts via 32KB LDS exchange after the loop. xconv writes
// per-tile GAP partials (no atomics); gate sums 49 partials.

#define BATCH 64
#define CH    64
#define HW_   3136            // 56*56
#define IMG_  (CH*HW_)        // 200704
#define NE    8
#define JOBS  128
#define PWSZ  36864           // per-expert packed weights: 36*2mt*2h*32m*8j (u16)
#define NTILE 13              // ceil(3136/256) position tiles
#define BD    4               // B-prefetch depth in steps (x2 frags = 8 loads)

typedef unsigned short u16;
typedef __attribute__((ext_vector_type(8))) short short8_t;   // 8 bf16 = 4 VGPR
typedef __attribute__((ext_vector_type(16))) float floatx16;  // 32x32 MFMA acc

__device__ u16   g_xb[(size_t)BATCH * IMG_];  // x bf16 NHWC [b][pos][ch]
__device__ u16   g_h[(size_t)JOBS * IMG_];    // conv1 out bf16 NHWC [job][pos][ch]
__device__ u16   g_pw1[NE * PWSZ];            // packed conv1 w (bn1_s folded)
__device__ u16   g_pw2[NE * PWSZ];            // packed conv2 w (bn2_s folded)
__device__ int   g_eid[JOBS];
__device__ float g_wgt[JOBS];
__device__ float g_pool[49 * BATCH * CH];     // GAP partials [tile49][b][ch]

__device__ __forceinline__ u16 f2b(float f) {
    unsigned v; __builtin_memcpy(&v, &f, 4);
    return (u16)((v + 0x7FFFu + ((v >> 16) & 1u)) >> 16);   // RNE
}

// ---------------- weight pre-pack -------------------------------------------
// packed[e][s36][mt][h][m][j] = w[e][M][ci][tap]*bn_s[e][M]
//   s36 = tap*4 + kq, ci = kq*16 + h*8 + j, M = mt*32 + m
__global__ __launch_bounds__(256) void pack_kernel(
    const float* __restrict__ w1, const float* __restrict__ s1,
    const float* __restrict__ w2, const float* __restrict__ s2)
{
    int idx = blockIdx.x * 256 + threadIdx.x;        // < 589824
    int conv = idx / 294912;
    int i2 = idx - conv * 294912;
    int e = i2 / PWSZ;   int r = i2 - e * PWSZ;
    int s36 = r >> 10;   int r2 = r & 1023;
    int mt  = r2 >> 9;   int r3 = r2 & 511;
    int h   = r3 >> 8;   int r4 = r3 & 255;
    int m   = r4 >> 3;   int j  = r4 & 7;
    int tap = s36 >> 2;
    int ci  = ((s36 & 3) << 4) | (h << 3) | j;
    int M   = mt*32 + m;
    const float* w  = conv ? w2 : w1;
    const float* sc = conv ? s2 : s1;
    float v = w[((e*64 + M)*64 + ci)*9 + tap] * sc[e*64 + M];
    (conv ? g_pw2 : g_pw1)[i2] = f2b(v);
}

// ---------------- x NCHW f32 -> g_xb NHWC bf16 + GAP partials ---------------
__global__ __launch_bounds__(256) void xconv_kernel(const float* __restrict__ x)
{
    __shared__ u16 T[64*66];          // stride 66 u16 -> conflict-free cols
    int b = blockIdx.y;
    int pos0 = blockIdx.x * 64;
    int tid = threadIdx.x;
    int pin = tid & 63;
    int c0 = tid >> 6;                // 0..3
    const float* xb = x + (size_t)b*IMG_ + pos0 + pin;
    #pragma unroll
    for (int i = 0; i < 16; i++) {
        int ch = c0*16 + i;
        T[pin*66 + ch] = f2b(xb[ch*HW_]);   // coalesced 256B f32 read per instr
    }
    __syncthreads();
    u16* ob = g_xb + (size_t)b*IMG_ + (size_t)pos0*64;
    #pragma unroll
    for (int i = 0; i < 16; i++) {
        int j = tid + i*256;          // 0..4095
        int ch = j & 63, pos = j >> 6;
        ob[pos*64 + ch] = T[pos*66 + ch];   // coalesced 512B write per instr
    }
    // GAP partial: threads 0..63 sum their channel over the 64 positions.
    // No atomics: per-tile partial, gate sums 49.
    if (tid < 64) {
        float s = 0.f;
        const float* xc = x + (size_t)b*IMG_ + tid*HW_ + pos0;
        #pragma unroll 4
        for (int p = 0; p < 64; p++) s += xc[p];
        g_pool[blockIdx.x*(BATCH*CH) + b*64 + tid] = s;
    }
}

// ---------------- gate finalize: pool -> logits -> top2 softmax -------------
__global__ __launch_bounds__(64) void gate_fin_kernel(
    const float* __restrict__ gw, const float* __restrict__ gb,
    float* __restrict__ dw_out)
{
    __shared__ float pooled[CH];
    __shared__ float logits[NE];
    int b = blockIdx.x, t = threadIdx.x;
    float s = 0.f;
    #pragma unroll
    for (int i = 0; i < 49; i++) s += g_pool[i*(BATCH*CH) + b*64 + t];
    pooled[t] = s * (1.f/3136.f);
    __syncthreads();
    if (t < NE) {
        float l = gb[t];
        for (int c = 0; c < CH; c++) l += pooled[c] * gw[t*CH + c];
        logits[t] = l;
    }
    __syncthreads();
    if (t == 0) {
        int i1 = 0; float v1 = logits[0];
        for (int e = 1; e < NE; e++) if (logits[e] > v1) { v1 = logits[e]; i1 = e; }
        int i2 = -1; float v2 = -3.4e38f;
        for (int e = 0; e < NE; e++) if (e != i1 && logits[e] > v2) { v2 = logits[e]; i2 = e; }
        float eb = __expf(v2 - v1);
        float wa = 1.f / (1.f + eb), wb = eb / (1.f + eb);
        for (int e = 0; e < NE; e++) dw_out[b*NE + e] = 0.f;
        dw_out[b*NE + i1] = wa;
        dw_out[b*NE + i2] = wb;
        g_eid[2*b] = i1; g_eid[2*b+1] = i2;
        g_wgt[2*b] = wa; g_wgt[2*b+1] = wb;
    }
}

// B-fragment loader for 32x32x16: lane holds pos=l31 (of its frag), k =
// kq*16 + h*8 + j.  `in` is pre-offset by h*8.  Clamp CSEd per tap.
__device__ __forceinline__ short8_t loadB32(
    const u16* __restrict__ in, int gn, int y, int xc, int tap, int kq)
{
    int dy = tap/3 - 1, dxk = tap - (tap/3)*3 - 1;
    int p = gn + dy*56 + dxk;
    bool vld = ((unsigned)(y + dy) < 56u) && ((unsigned)(xc + dxk) < 56u);
    int pc = p < 0 ? 0 : (p > 3135 ? 3135 : p);
    short8_t t = *(const short8_t*)(in + pc*64 + kq*16);
    const short8_t zero = {};
    return vld ? t : zero;
}

// Single-shot A stage: both experts' mt-slice, 72KB = 4608 16B-units,
// 9 rounds of 512 threads. AL layout: [s36][es][h][m32][j8] (512 u16 per
// slice-es; a wave's ds_read_b128 covers 1KB contiguous -> conflict-free).
__device__ __forceinline__ void stageA(
    u16* AL, const u16* __restrict__ pw0, const u16* __restrict__ pw1,
    int mt, int tid)
{
    short8_t st[9];
    #pragma unroll
    for (int i = 0; i < 9; i++) {
        int u = i*512 + tid;
        int es = u >= 2304;
        int r = u - (es ? 2304 : 0);
        int s36 = r >> 6;
        int c = r & 63;
        st[i] = *(const short8_t*)((es ? pw1 : pw0) + s36*1024 + mt*512 + c*8);
    }
    #pragma unroll
    for (int i = 0; i < 9; i++) {
        int u = i*512 + tid;
        int es = u >= 2304;
        int r = u - (es ? 2304 : 0);
        int s36 = r >> 6;
        int c = r & 63;
        *(short8_t*)(AL + (s36*2 + es)*512 + c*8) = st[i];
    }
}

// ---------------- conv1 + bn1 + relu -> g_h ---------------------------------
// grid (NTILE, 2, BATCH): x=pos tile (256), y=mt (32 out-ch), z=batch.
__global__ __launch_bounds__(512, 4) void conv1_kernel(const float* __restrict__ b1)
{
    __shared__ u16 AL[36864];           // 72KB, staged once
    int tile = blockIdx.x;
    int mt   = blockIdx.y;
    int b    = blockIdx.z;
    int e0 = g_eid[2*b], e1 = g_eid[2*b+1];
    int tid = threadIdx.x;
    int lane = tid & 63, w = tid >> 6;  // 8 waves
    int es = w & 1, pg = w >> 1;        // expert slot (2), position group (4)
    int l31 = lane & 31, h = lane >> 5;
    int gn0 = tile*256 + pg*64 + l31;   // frag 0 position (may be >= 3136)
    int gn1 = gn0 + 32;                 // frag 1 position
    int y0 = gn0/56, xc0 = gn0 - y0*56;
    int y1 = gn1/56, xc1 = gn1 - y1*56;
    int e = es ? e1 : e0;
    const u16* in  = g_xb + (size_t)b*IMG_ + h*8;
    const u16* pw0 = g_pw1 + e0*PWSZ;
    const u16* pw1 = g_pw1 + e1*PWSZ;
    int aOff = es*512 + h*256 + l31*8;  // + s*1024

    floatx16 accA = {}, accB = {};      // frag 0 / frag 1 accumulators
    short8_t B0[BD], B1[BD];
    #pragma unroll
    for (int s = 0; s < BD; s++) {      // B prefetch issues FIRST (overlaps stage)
        B0[s] = loadB32(in, gn0, y0, xc0, s >> 2, s & 3);
        B1[s] = loadB32(in, gn1, y1, xc1, s >> 2, s & 3);
    }
    stageA(AL, pw0, pw1, mt, tid);
    __syncthreads();                    // the ONLY barrier

    #pragma unroll
    for (int s = 0; s < 36; s++) {
        short8_t a = *(const short8_t*)(AL + s*1024 + aOff);
        accA = __builtin_amdgcn_mfma_f32_32x32x16_bf16(a, B0[s & (BD-1)], accA, 0, 0, 0);
        accB = __builtin_amdgcn_mfma_f32_32x32x16_bf16(a, B1[s & (BD-1)], accB, 0, 0, 0);
        int sp = s + BD;
        if (sp < 36) {
            B0[s & (BD-1)] = loadB32(in, gn0, y0, xc0, sp >> 2, sp & 3);
            B1[s & (BD-1)] = loadB32(in, gn1, y1, xc1, sp >> 2, sp & 3);
        }
    }

    u16* hb = g_h + (size_t)(2*b + es)*IMG_ + mt*32;
    #pragma unroll
    for (int f = 0; f < 2; f++) {
        int gn = f ? gn1 : gn0;
        if (gn < HW_) {
            u16* hp = hb + (size_t)gn*64;
            #pragma unroll
            for (int rg = 0; rg < 4; rg++) {
                union { u16 u[4]; uint2 v; } t;
                #pragma unroll
                for (int rr = 0; rr < 4; rr++) {
                    int m = rg*8 + h*4 + rr;       // D row = (reg&3)+8*(reg>>2)+4*h
                    float v = (f ? accB : accA)[rg*4 + rr] + b1[e*64 + mt*32 + m];
                    t.u[rr] = f2b(fmaxf(v, 0.f));
                }
                *(uint2*)(hp + rg*8 + h*4) = t.v;
            }
        }
    }
}

// ---------------- conv2 + bn2 + residual + cross-wave combine ---------------
__global__ __launch_bounds__(512, 4) void conv2_kernel(
    const float* __restrict__ x, const float* __restrict__ b2,
    float* __restrict__ out)
{
    __shared__ u16 AL[36864];           // 72KB; reused as 32KB f32 P after loop
    int tile = (NTILE-1) - blockIdx.x;  // REVERSED: read newest h first (L2 LIFO)
    int mt   = blockIdx.y;
    int b    = 63 - blockIdx.z;
    int e0 = g_eid[2*b], e1 = g_eid[2*b+1];
    int tid = threadIdx.x;
    int lane = tid & 63, w = tid >> 6;
    int es = w & 1, pg = w >> 1;
    int l31 = lane & 31, h = lane >> 5;
    int gn0 = tile*256 + pg*64 + l31;
    int gn1 = gn0 + 32;
    int y0 = gn0/56, xc0 = gn0 - y0*56;
    int y1 = gn1/56, xc1 = gn1 - y1*56;
    int e = es ? e1 : e0;
    float wgt = g_wgt[2*b + es];
    const u16* in  = g_h + (size_t)(2*b + es)*IMG_ + h*8;  // own expert stream
    const u16* pw0 = g_pw2 + e0*PWSZ;
    const u16* pw1 = g_pw2 + e1*PWSZ;
    int aOff = es*512 + h*256 + l31*8;

    floatx16 accA = {}, accB = {};
    short8_t B0[BD], B1[BD];
    #pragma unroll
    for (int s = 0; s < BD; s++) {
        B0[s] = loadB32(in, gn0, y0, xc0, s >> 2, s & 3);
        B1[s] = loadB32(in, gn1, y1, xc1, s >> 2, s & 3);
    }
    stageA(AL, pw0, pw1, mt, tid);
    __syncthreads();

    #pragma unroll
    for (int s = 0; s < 36; s++) {
        short8_t a = *(const short8_t*)(AL + s*1024 + aOff);
        accA = __builtin_amdgcn_mfma_f32_32x32x16_bf16(a, B0[s & (BD-1)], accA, 0, 0, 0);
        accB = __builtin_amdgcn_mfma_f32_32x32x16_bf16(a, B1[s & (BD-1)], accB, 0, 0, 0);
        int sp = s + BD;
        if (sp < 36) {
            B0[s & (BD-1)] = loadB32(in, gn0, y0, xc0, sp >> 2, sp & 3);
            B1[s & (BD-1)] = loadB32(in, gn1, y1, xc1, sp >> 2, sp & 3);
        }
    }

    // combine: es0 waves drop w0*relu(y0+x) into LDS, es1 waves add+store.
    __syncthreads();                    // all waves done reading AL
    float* P = (float*)AL;              // [pg][f][m32][l31] f32 = 32KB
    const float* xb = x + (size_t)b*IMG_ + (size_t)(mt*32)*HW_;
    if (es == 0) {
        #pragma unroll
        for (int f = 0; f < 2; f++) {
            int gn = f ? gn1 : gn0;
            if (gn < HW_) {
                #pragma unroll
                for (int rg = 0; rg < 4; rg++)
                    #pragma unroll
                    for (int rr = 0; rr < 4; rr++) {
                        int m = rg*8 + h*4 + rr;
                        float v = (f ? accB : accA)[rg*4 + rr] + b2[e*64 + mt*32 + m]
                                  + xb[(size_t)m*HW_ + gn];
                        P[((pg*2 + f)*32 + m)*32 + l31] = wgt * fmaxf(v, 0.f);
                    }
            }
        }
    }
    __syncthreads();
    if (es == 1) {
        float* ob = out + (size_t)b*IMG_ + (size_t)(mt*32)*HW_;
        #pragma unroll
        for (int f = 0; f < 2; f++) {
            int gn = f ? gn1 : gn0;
            if (gn < HW_) {
                #pragma unroll
                for (int rg = 0; rg < 4; rg++)
                    #pragma unroll
                    for (int rr = 0; rr < 4; rr++) {
                        int m = rg*8 + h*4 + rr;
                        float v = (f ? accB : accA)[rg*4 + rr] + b2[e*64 + mt*32 + m]
                                  + xb[(size_t)m*HW_ + gn];
                        ob[(size_t)m*HW_ + gn] = wgt * fmaxf(v, 0.f)
                                                 + P[((pg*2 + f)*32 + m)*32 + l31];
                    }
            }
        }
    }
}

extern "C" void kernel_launch(void* const* d_in, const int* in_sizes, int n_in,
                              void* d_out, int out_size, void* d_ws, size_t ws_size,
                              hipStream_t stream) {
    const float* x   = (const float*)d_in[0];
    const float* gw  = (const float*)d_in[1];
    const float* gb  = (const float*)d_in[2];
    const float* w1  = (const float*)d_in[3];
    const float* s1  = (const float*)d_in[4];
    const float* b1  = (const float*)d_in[5];
    const float* w2  = (const float*)d_in[6];
    const float* s2  = (const float*)d_in[7];
    const float* b2  = (const float*)d_in[8];
    float* out = (float*)d_out;
    float* dw  = out + (size_t)BATCH * IMG_;   // dense_w region of d_out (f32)

    (void)d_ws; (void)ws_size;                 // zero d_ws usage (R1/R2 aborts)

    hipLaunchKernelGGL(pack_kernel, dim3(2304), dim3(256), 0, stream, w1, s1, w2, s2);
    hipLaunchKernelGGL(xconv_kernel, dim3(49, BATCH), dim3(256), 0, stream, x);
    hipLaunchKernelGGL(gate_fin_kernel, dim3(BATCH), dim3(64), 0, stream, gw, gb, dw);
    hipLaunchKernelGGL(conv1_kernel, dim3(NTILE, 2, BATCH), dim3(512), 0, stream, b1);
    hipLaunchKernelGGL(conv2_kernel, dim3(NTILE, 2, BATCH), dim3(512), 0, stream, x, b2, out);
}

// Round 5
// 398.168 us; speedup vs baseline: 1.0326x; 1.0326x over previous
//
#include <hip/hip_runtime.h>

// ResNetBlock_MoE: B=64,C=64,H=W=56,E=8,TOPK=2. f32 in / f32 out.
// out = sum_k w_k*relu(bn2(conv2(relu(bn1(conv1(x,e)))))+x), plus dense_w.
//
// R16: R15 correctness fix — the B-refill was moved before the consuming
// MFMA, clobbering the live slot (mfma read slice s+4 instead of s; absmax
// 4.17). Fix: capture bb0/bb1 from the rolling buffer BEFORE the refill
// loads, MFMA on the captured values (register rename makes copies free).
// Unchanged from R15 (untested there due to the bug):
//  1. XCD-chunked bijective swizzle (1664 = 8*208): (tile,mt) pairs adjacent
//     on the SAME XCD -> mt-duplicate B reads L2-hit; conv2 keeps conv1's
//     b->XCD mapping (h read from the L2 that wrote it), tile-LIFO only.
//  2. Explicit A-register pipeline depth 3 (load A[s+3] while computing s):
//     covers the ds_read->MFMA lgkmcnt latency the compiler wasn't hoisting
//     (VGPR=52 in R12-R14 = no hoist, flat ~13% MfmaUtil).
// Keeps: barrier-free 36-step loop (single 72KB A stage), wave = 1 expert x
// 32 out-ch x 64 pos (2 B frags, depth-4 each), conv2 LDS combine, no atomics.

#define BATCH 64
#define CH    64
#define HW_   3136            // 56*56
#define IMG_  (CH*HW_)        // 200704
#define NE    8
#define JOBS  128
#define PWSZ  36864           // per-expert packed weights: 36*2mt*2h*32m*8j (u16)
#define NTILE 13              // ceil(3136/256) position tiles
#define BD    4               // B-prefetch depth in steps (x2 frags = 8 loads)
#define CGRID (NTILE*2*BATCH) // 1664 = 8 XCDs * 208

typedef unsigned short u16;
typedef __attribute__((ext_vector_type(8))) short short8_t;   // 8 bf16 = 4 VGPR
typedef __attribute__((ext_vector_type(16))) float floatx16;  // 32x32 MFMA acc

__device__ u16   g_xb[(size_t)BATCH * IMG_];  // x bf16 NHWC [b][pos][ch]
__device__ u16   g_h[(size_t)JOBS * IMG_];    // conv1 out bf16 NHWC [job][pos][ch]
__device__ u16   g_pw1[NE * PWSZ];            // packed conv1 w (bn1_s folded)
__device__ u16   g_pw2[NE * PWSZ];            // packed conv2 w (bn2_s folded)
__device__ int   g_eid[JOBS];
__device__ float g_wgt[JOBS];
__device__ float g_pool[49 * BATCH * CH];     // GAP partials [tile49][b][ch]

__device__ __forceinline__ u16 f2b(float f) {
    unsigned v; __builtin_memcpy(&v, &f, 4);
    return (u16)((v + 0x7FFFu + ((v >> 16) & 1u)) >> 16);   // RNE
}

// ---------------- weight pre-pack -------------------------------------------
// packed[e][s36][mt][h][m][j] = w[e][M][ci][tap]*bn_s[e][M]
//   s36 = tap*4 + kq, ci = kq*16 + h*8 + j, M = mt*32 + m
__global__ __launch_bounds__(256) void pack_kernel(
    const float* __restrict__ w1, const float* __restrict__ s1,
    const float* __restrict__ w2, const float* __restrict__ s2)
{
    int idx = blockIdx.x * 256 + threadIdx.x;        // < 589824
    int conv = idx / 294912;
    int i2 = idx - conv * 294912;
    int e = i2 / PWSZ;   int r = i2 - e * PWSZ;
    int s36 = r >> 10;   int r2 = r & 1023;
    int mt  = r2 >> 9;   int r3 = r2 & 511;
    int h   = r3 >> 8;   int r4 = r3 & 255;
    int m   = r4 >> 3;   int j  = r4 & 7;
    int tap = s36 >> 2;
    int ci  = ((s36 & 3) << 4) | (h << 3) | j;
    int M   = mt*32 + m;
    const float* w  = conv ? w2 : w1;
    const float* sc = conv ? s2 : s1;
    float v = w[((e*64 + M)*64 + ci)*9 + tap] * sc[e*64 + M];
    (conv ? g_pw2 : g_pw1)[i2] = f2b(v);
}

// ---------------- x NCHW f32 -> g_xb NHWC bf16 + GAP partials ---------------
__global__ __launch_bounds__(256) void xconv_kernel(const float* __restrict__ x)
{
    __shared__ u16 T[64*66];          // stride 66 u16 -> conflict-free cols
    int b = blockIdx.y;
    int pos0 = blockIdx.x * 64;
    int tid = threadIdx.x;
    int pin = tid & 63;
    int c0 = tid >> 6;                // 0..3
    const float* xb = x + (size_t)b*IMG_ + pos0 + pin;
    #pragma unroll
    for (int i = 0; i < 16; i++) {
        int ch = c0*16 + i;
        T[pin*66 + ch] = f2b(xb[ch*HW_]);   // coalesced 256B f32 read per instr
    }
    __syncthreads();
    u16* ob = g_xb + (size_t)b*IMG_ + (size_t)pos0*64;
    #pragma unroll
    for (int i = 0; i < 16; i++) {
        int j = tid + i*256;          // 0..4095
        int ch = j & 63, pos = j >> 6;
        ob[pos*64 + ch] = T[pos*66 + ch];   // coalesced 512B write per instr
    }
    // GAP partial: threads 0..63 sum their channel over the 64 positions.
    if (tid < 64) {
        float s = 0.f;
        const float* xc = x + (size_t)b*IMG_ + tid*HW_ + pos0;
        #pragma unroll 4
        for (int p = 0; p < 64; p++) s += xc[p];
        g_pool[blockIdx.x*(BATCH*CH) + b*64 + tid] = s;
    }
}

// ---------------- gate finalize: pool -> logits -> top2 softmax -------------
__global__ __launch_bounds__(64) void gate_fin_kernel(
    const float* __restrict__ gw, const float* __restrict__ gb,
    float* __restrict__ dw_out)
{
    __shared__ float pooled[CH];
    __shared__ float logits[NE];
    int b = blockIdx.x, t = threadIdx.x;
    float s = 0.f;
    #pragma unroll
    for (int i = 0; i < 49; i++) s += g_pool[i*(BATCH*CH) + b*64 + t];
    pooled[t] = s * (1.f/3136.f);
    __syncthreads();
    if (t < NE) {
        float l = gb[t];
        for (int c = 0; c < CH; c++) l += pooled[c] * gw[t*CH + c];
        logits[t] = l;
    }
    __syncthreads();
    if (t == 0) {
        int i1 = 0; float v1 = logits[0];
        for (int e = 1; e < NE; e++) if (logits[e] > v1) { v1 = logits[e]; i1 = e; }
        int i2 = -1; float v2 = -3.4e38f;
        for (int e = 0; e < NE; e++) if (e != i1 && logits[e] > v2) { v2 = logits[e]; i2 = e; }
        float eb = __expf(v2 - v1);
        float wa = 1.f / (1.f + eb), wb = eb / (1.f + eb);
        for (int e = 0; e < NE; e++) dw_out[b*NE + e] = 0.f;
        dw_out[b*NE + i1] = wa;
        dw_out[b*NE + i2] = wb;
        g_eid[2*b] = i1; g_eid[2*b+1] = i2;
        g_wgt[2*b] = wa; g_wgt[2*b+1] = wb;
    }
}

// B-fragment loader for 32x32x16: lane holds pos=l31 (of its frag), k =
// kq*16 + h*8 + j.  `in` is pre-offset by h*8.  Clamp CSEd per tap.
__device__ __forceinline__ short8_t loadB32(
    const u16* __restrict__ in, int gn, int y, int xc, int tap, int kq)
{
    int dy = tap/3 - 1, dxk = tap - (tap/3)*3 - 1;
    int p = gn + dy*56 + dxk;
    bool vld = ((unsigned)(y + dy) < 56u) && ((unsigned)(xc + dxk) < 56u);
    int pc = p < 0 ? 0 : (p > 3135 ? 3135 : p);
    short8_t t = *(const short8_t*)(in + pc*64 + kq*16);
    const short8_t zero = {};
    return vld ? t : zero;
}

// Single-shot A stage: both experts' mt-slice, 72KB = 4608 16B-units,
// 9 rounds of 512 threads. AL layout: [s36][es][h][m32][j8].
__device__ __forceinline__ void stageA(
    u16* AL, const u16* __restrict__ pw0, const u16* __restrict__ pw1,
    int mt, int tid)
{
    short8_t st[9];
    #pragma unroll
    for (int i = 0; i < 9; i++) {
        int u = i*512 + tid;
        int es = u >= 2304;
        int r = u - (es ? 2304 : 0);
        int s36 = r >> 6;
        int c = r & 63;
        st[i] = *(const short8_t*)((es ? pw1 : pw0) + s36*1024 + mt*512 + c*8);
    }
    #pragma unroll
    for (int i = 0; i < 9; i++) {
        int u = i*512 + tid;
        int es = u >= 2304;
        int r = u - (es ? 2304 : 0);
        int s36 = r >> 6;
        int c = r & 63;
        *(short8_t*)(AL + (s36*2 + es)*512 + c*8) = st[i];
    }
}

// ---------------- conv1 + bn1 + relu -> g_h ---------------------------------
// 1D grid 1664, XCD-chunked decode: L = (wg&7)*208 + wg/8; b = L/26,
// tile = (L%26)>>1, mt = L&1 -> (tile,mt) pairs adjacent on one XCD.
__global__ __launch_bounds__(512, 4) void conv1_kernel(const float* __restrict__ b1)
{
    __shared__ u16 AL[36864];           // 72KB, staged once
    int wg = blockIdx.x;
    int L  = (wg & 7) * (CGRID/8) + (wg >> 3);
    int b  = L / 26;
    int r  = L - b*26;
    int tile = r >> 1;
    int mt   = r & 1;
    int e0 = g_eid[2*b], e1 = g_eid[2*b+1];
    int tid = threadIdx.x;
    int lane = tid & 63, w = tid >> 6;  // 8 waves
    int es = w & 1, pg = w >> 1;        // expert slot (2), position group (4)
    int l31 = lane & 31, h = lane >> 5;
    int gn0 = tile*256 + pg*64 + l31;   // frag 0 position (may be >= 3136)
    int gn1 = gn0 + 32;                 // frag 1 position
    int y0 = gn0/56, xc0 = gn0 - y0*56;
    int y1 = gn1/56, xc1 = gn1 - y1*56;
    int e = es ? e1 : e0;
    const u16* in  = g_xb + (size_t)b*IMG_ + h*8;
    const u16* pw0 = g_pw1 + e0*PWSZ;
    const u16* pw1 = g_pw1 + e1*PWSZ;
    int aOff = es*512 + h*256 + l31*8;  // + s*1024

    floatx16 accA = {}, accB = {};      // frag 0 / frag 1 accumulators
    short8_t B0[BD], B1[BD];
    #pragma unroll
    for (int s = 0; s < BD; s++) {      // B prefetch issues FIRST (longest latency)
        B0[s] = loadB32(in, gn0, y0, xc0, s >> 2, s & 3);
        B1[s] = loadB32(in, gn1, y1, xc1, s >> 2, s & 3);
    }
    stageA(AL, pw0, pw1, mt, tid);
    __syncthreads();                    // the ONLY barrier

    short8_t Ar[3];                     // A register pipeline, depth 3
    #pragma unroll
    for (int i = 0; i < 3; i++)
        Ar[i] = *(const short8_t*)(AL + i*1024 + aOff);

    #pragma unroll
    for (int s = 0; s < 36; s++) {
        short8_t bb0 = B0[s & (BD-1)];  // capture BEFORE refill (R15 bug fix)
        short8_t bb1 = B1[s & (BD-1)];
        int sp = s + BD;
        if (sp < 36) {                  // refill issues ahead of the MFMAs
            B0[s & (BD-1)] = loadB32(in, gn0, y0, xc0, sp >> 2, sp & 3);
            B1[s & (BD-1)] = loadB32(in, gn1, y1, xc1, sp >> 2, sp & 3);
        }
        short8_t a = Ar[s % 3];
        if (s + 3 < 36)                 // A refill 3 steps ahead (lgkmcnt cover)
            Ar[s % 3] = *(const short8_t*)(AL + (s+3)*1024 + aOff);
        accA = __builtin_amdgcn_mfma_f32_32x32x16_bf16(a, bb0, accA, 0, 0, 0);
        accB = __builtin_amdgcn_mfma_f32_32x32x16_bf16(a, bb1, accB, 0, 0, 0);
    }

    u16* hb = g_h + (size_t)(2*b + es)*IMG_ + mt*32;
    #pragma unroll
    for (int f = 0; f < 2; f++) {
        int gn = f ? gn1 : gn0;
        if (gn < HW_) {
            u16* hp = hb + (size_t)gn*64;
            #pragma unroll
            for (int rg = 0; rg < 4; rg++) {
                union { u16 u[4]; uint2 v; } t;
                #pragma unroll
                for (int rr = 0; rr < 4; rr++) {
                    int m = rg*8 + h*4 + rr;       // D row = (reg&3)+8*(reg>>2)+4*h
                    float v = (f ? accB : accA)[rg*4 + rr] + b1[e*64 + mt*32 + m];
                    t.u[rr] = f2b(fmaxf(v, 0.f));
                }
                *(uint2*)(hp + rg*8 + h*4) = t.v;
            }
        }
    }
}

// ---------------- conv2 + bn2 + residual + cross-wave combine ---------------
__global__ __launch_bounds__(512, 4) void conv2_kernel(
    const float* __restrict__ x, const float* __restrict__ b2,
    float* __restrict__ out)
{
    __shared__ u16 AL[36864];           // 72KB; reused as 32KB f32 P after loop
    int wg = blockIdx.x;
    int L  = (wg & 7) * (CGRID/8) + (wg >> 3);
    int b  = L / 26;                    // SAME b->XCD map as conv1 (h L2 reuse)
    int r  = L - b*26;
    int tile = (NTILE-1) - (r >> 1);    // tile-LIFO within b (newest h first)
    int mt   = r & 1;
    int e0 = g_eid[2*b], e1 = g_eid[2*b+1];
    int tid = threadIdx.x;
    int lane = tid & 63, w = tid >> 6;
    int es = w & 1, pg = w >> 1;
    int l31 = lane & 31, h = lane >> 5;
    int gn0 = tile*256 + pg*64 + l31;
    int gn1 = gn0 + 32;
    int y0 = gn0/56, xc0 = gn0 - y0*56;
    int y1 = gn1/56, xc1 = gn1 - y1*56;
    int e = es ? e1 : e0;
    float wgt = g_wgt[2*b + es];
    const u16* in  = g_h + (size_t)(2*b + es)*IMG_ + h*8;  // own expert stream
    const u16* pw0 = g_pw2 + e0*PWSZ;
    const u16* pw1 = g_pw2 + e1*PWSZ;
    int aOff = es*512 + h*256 + l31*8;

    floatx16 accA = {}, accB = {};
    short8_t B0[BD], B1[BD];
    #pragma unroll
    for (int s = 0; s < BD; s++) {
        B0[s] = loadB32(in, gn0, y0, xc0, s >> 2, s & 3);
        B1[s] = loadB32(in, gn1, y1, xc1, s >> 2, s & 3);
    }
    stageA(AL, pw0, pw1, mt, tid);
    __syncthreads();

    short8_t Ar[3];
    #pragma unroll
    for (int i = 0; i < 3; i++)
        Ar[i] = *(const short8_t*)(AL + i*1024 + aOff);

    #pragma unroll
    for (int s = 0; s < 36; s++) {
        short8_t bb0 = B0[s & (BD-1)];  // capture BEFORE refill (R15 bug fix)
        short8_t bb1 = B1[s & (BD-1)];
        int sp = s + BD;
        if (sp < 36) {
            B0[s & (BD-1)] = loadB32(in, gn0, y0, xc0, sp >> 2, sp & 3);
            B1[s & (BD-1)] = loadB32(in, gn1, y1, xc1, sp >> 2, sp & 3);
        }
        short8_t a = Ar[s % 3];
        if (s + 3 < 36)
            Ar[s % 3] = *(const short8_t*)(AL + (s+3)*1024 + aOff);
        accA = __builtin_amdgcn_mfma_f32_32x32x16_bf16(a, bb0, accA, 0, 0, 0);
        accB = __builtin_amdgcn_mfma_f32_32x32x16_bf16(a, bb1, accB, 0, 0, 0);
    }

    // combine: es0 waves drop w0*relu(y0+x) into LDS, es1 waves add+store.
    __syncthreads();                    // all waves done reading AL
    float* P = (float*)AL;              // [pg][f][m32][l31] f32 = 32KB
    const float* xb = x + (size_t)b*IMG_ + (size_t)(mt*32)*HW_;
    if (es == 0) {
        #pragma unroll
        for (int f = 0; f < 2; f++) {
            int gn = f ? gn1 : gn0;
            if (gn < HW_) {
                #pragma unroll
                for (int rg = 0; rg < 4; rg++)
                    #pragma unroll
                    for (int rr = 0; rr < 4; rr++) {
                        int m = rg*8 + h*4 + rr;
                        float v = (f ? accB : accA)[rg*4 + rr] + b2[e*64 + mt*32 + m]
                                  + xb[(size_t)m*HW_ + gn];
                        P[((pg*2 + f)*32 + m)*32 + l31] = wgt * fmaxf(v, 0.f);
                    }
            }
        }
    }
    __syncthreads();
    if (es == 1) {
        float* ob = out + (size_t)b*IMG_ + (size_t)(mt*32)*HW_;
        #pragma unroll
        for (int f = 0; f < 2; f++) {
            int gn = f ? gn1 : gn0;
            if (gn < HW_) {
                #pragma unroll
                for (int rg = 0; rg < 4; rg++)
                    #pragma unroll
                    for (int rr = 0; rr < 4; rr++) {
                        int m = rg*8 + h*4 + rr;
                        float v = (f ? accB : accA)[rg*4 + rr] + b2[e*64 + mt*32 + m]
                                  + xb[(size_t)m*HW_ + gn];
                        ob[(size_t)m*HW_ + gn] = wgt * fmaxf(v, 0.f)
                                                 + P[((pg*2 + f)*32 + m)*32 + l31];
                    }
            }
        }
    }
}

extern "C" void kernel_launch(void* const* d_in, const int* in_sizes, int n_in,
                              void* d_out, int out_size, void* d_ws, size_t ws_size,
                              hipStream_t stream) {
    const float* x   = (const float*)d_in[0];
    const float* gw  = (const float*)d_in[1];
    const float* gb  = (const float*)d_in[2];
    const float* w1  = (const float*)d_in[3];
    const float* s1  = (const float*)d_in[4];
    const float* b1  = (const float*)d_in[5];
    const float* w2  = (const float*)d_in[6];
    const float* s2  = (const float*)d_in[7];
    const float* b2  = (const float*)d_in[8];
    float* out = (float*)d_out;
    float* dw  = out + (size_t)BATCH * IMG_;   // dense_w region of d_out (f32)

    (void)d_ws; (void)ws_size;                 // zero d_ws usage (R1/R2 aborts)

    hipLaunchKernelGGL(pack_kernel, dim3(2304), dim3(256), 0, stream, w1, s1, w2, s2);
    hipLaunchKernelGGL(xconv_kernel, dim3(49, BATCH), dim3(256), 0, stream, x);
    hipLaunchKernelGGL(gate_fin_kernel, dim3(BATCH), dim3(64), 0, stream, gw, gb, dw);
    hipLaunchKernelGGL(conv1_kernel, dim3(CGRID), dim3(512), 0, stream, b1);
    hipLaunchKernelGGL(conv2_kernel, dim3(CGRID), dim3(512), 0, stream, x, b2, out);
}

// Round 7
// 241.604 us; speedup vs baseline: 1.7017x; 1.6480x over previous
//
#include <hip/hip_runtime.h>

// ResNetBlock_MoE: B=64,C=64,H=W=56,E=8,TOPK=2. f32 in / f32 out.
// out = sum_k w_k*relu(bn2(conv2(relu(bn1(conv1(x,e)))))+x), plus dense_w.
//
// R18 = R17 resubmit (R17 bench died on container acquisition, kernel never
// ran; source re-audited, no changes).
// R17: R16 post-mortem — FETCH dropped to 54MB (swizzle worked) but time
// didn't: the wall is L2 traffic from B-load line waste. NHWC [pos][64ch]
// puts a k-slice (32B) inside a 128B record -> 64-lane load touches 32 lines
// using 32B each (4x over-fetch), and tap re-reads thrash L1 (~66KB vs 32KB).
// Model: 128KB/step/CU from L2 ~= 2300cy/step ~= 114us — matches 146 measured.
// Fix: kq-plane-major activations [b][kq4][pos][ch16] for g_xb and g_h ->
// B wave-load = 32pos x 32B CONTIGUOUS (full lines, 4x less L2), per-tap
// plane = 8KB/block -> L1-resident -> tap re-reads L1-hit.
// Also: B-prefetch depth 6 (12 outstanding, ~117 VGPR <= 128), s%BD fix.
// Keeps: barrier-free 36-step loop, conflict-free A LDS, XCD-chunked swizzle,
// A-register pipeline depth 3, conv2 LDS combine, capture-before-refill.

#define BATCH 64
#define CH    64
#define HW_   3136            // 56*56
#define IMG_  (CH*HW_)        // 200704
#define PLANE (HW_*16)        // 50176 u16: one kq-plane [pos][ch16]
#define NE    8
#define JOBS  128
#define PWSZ  36864           // per-expert packed weights: 36*2mt*2h*32m*8j (u16)
#define NTILE 13              // ceil(3136/256) position tiles
#define BD    6               // B-prefetch depth in steps (x2 frags = 12 loads)
#define CGRID (NTILE*2*BATCH) // 1664 = 8 XCDs * 208

typedef unsigned short u16;
typedef __attribute__((ext_vector_type(8))) short short8_t;   // 8 bf16 = 4 VGPR
typedef __attribute__((ext_vector_type(16))) float floatx16;  // 32x32 MFMA acc

__device__ u16   g_xb[(size_t)BATCH * IMG_];  // x bf16 [b][kq][pos][ch16]
__device__ u16   g_h[(size_t)JOBS * IMG_];    // conv1 out bf16 [job][kq][pos][ch16]
__device__ u16   g_pw1[NE * PWSZ];            // packed conv1 w (bn1_s folded)
__device__ u16   g_pw2[NE * PWSZ];            // packed conv2 w (bn2_s folded)
__device__ int   g_eid[JOBS];
__device__ float g_wgt[JOBS];
__device__ float g_pool[49 * BATCH * CH];     // GAP partials [tile49][b][ch]

__device__ __forceinline__ u16 f2b(float f) {
    unsigned v; __builtin_memcpy(&v, &f, 4);
    return (u16)((v + 0x7FFFu + ((v >> 16) & 1u)) >> 16);   // RNE
}

// ---------------- weight pre-pack -------------------------------------------
// packed[e][s36][mt][h][m][j] = w[e][M][ci][tap]*bn_s[e][M]
//   s36 = tap*4 + kq, ci = kq*16 + h*8 + j, M = mt*32 + m
__global__ __launch_bounds__(256) void pack_kernel(
    const float* __restrict__ w1, const float* __restrict__ s1,
    const float* __restrict__ w2, const float* __restrict__ s2)
{
    int idx = blockIdx.x * 256 + threadIdx.x;        // < 589824
    int conv = idx / 294912;
    int i2 = idx - conv * 294912;
    int e = i2 / PWSZ;   int r = i2 - e * PWSZ;
    int s36 = r >> 10;   int r2 = r & 1023;
    int mt  = r2 >> 9;   int r3 = r2 & 511;
    int h   = r3 >> 8;   int r4 = r3 & 255;
    int m   = r4 >> 3;   int j  = r4 & 7;
    int tap = s36 >> 2;
    int ci  = ((s36 & 3) << 4) | (h << 3) | j;
    int M   = mt*32 + m;
    const float* w  = conv ? w2 : w1;
    const float* sc = conv ? s2 : s1;
    float v = w[((e*64 + M)*64 + ci)*9 + tap] * sc[e*64 + M];
    (conv ? g_pw2 : g_pw1)[i2] = f2b(v);
}

// ---------------- x NCHW f32 -> g_xb [kq][pos][ch16] bf16 + GAP partials ----
__global__ __launch_bounds__(256) void xconv_kernel(const float* __restrict__ x)
{
    __shared__ u16 T[64*66];          // [pos][ch], stride 66
    int b = blockIdx.y;
    int pos0 = blockIdx.x * 64;
    int tid = threadIdx.x;
    int pin = tid & 63;
    int c0 = tid >> 6;                // 0..3
    const float* xb = x + (size_t)b*IMG_ + pos0 + pin;
    #pragma unroll
    for (int i = 0; i < 16; i++) {
        int ch = c0*16 + i;
        T[pin*66 + ch] = f2b(xb[ch*HW_]);   // coalesced 256B f32 read per instr
    }
    __syncthreads();
    u16* ob = g_xb + (size_t)b*IMG_ + (size_t)pos0*16;   // within-plane offset
    #pragma unroll
    for (int i = 0; i < 16; i++) {
        int j = tid + i*256;          // 0..4095
        int kq  = j >> 10;
        int pos = (j >> 4) & 63;
        int c16 = j & 15;
        ob[(size_t)kq*PLANE + pos*16 + c16] = T[pos*66 + kq*16 + c16];
    }
    // GAP partial: threads 0..63 sum their channel over the 64 positions.
    if (tid < 64) {
        float s = 0.f;
        const float* xc = x + (size_t)b*IMG_ + tid*HW_ + pos0;
        #pragma unroll 4
        for (int p = 0; p < 64; p++) s += xc[p];
        g_pool[blockIdx.x*(BATCH*CH) + b*64 + tid] = s;
    }
}

// ---------------- gate finalize: pool -> logits -> top2 softmax -------------
__global__ __launch_bounds__(64) void gate_fin_kernel(
    const float* __restrict__ gw, const float* __restrict__ gb,
    float* __restrict__ dw_out)
{
    __shared__ float pooled[CH];
    __shared__ float logits[NE];
    int b = blockIdx.x, t = threadIdx.x;
    float s = 0.f;
    #pragma unroll
    for (int i = 0; i < 49; i++) s += g_pool[i*(BATCH*CH) + b*64 + t];
    pooled[t] = s * (1.f/3136.f);
    __syncthreads();
    if (t < NE) {
        float l = gb[t];
        for (int c = 0; c < CH; c++) l += pooled[c] * gw[t*CH + c];
        logits[t] = l;
    }
    __syncthreads();
    if (t == 0) {
        int i1 = 0; float v1 = logits[0];
        for (int e = 1; e < NE; e++) if (logits[e] > v1) { v1 = logits[e]; i1 = e; }
        int i2 = -1; float v2 = -3.4e38f;
        for (int e = 0; e < NE; e++) if (e != i1 && logits[e] > v2) { v2 = logits[e]; i2 = e; }
        float eb = __expf(v2 - v1);
        float wa = 1.f / (1.f + eb), wb = eb / (1.f + eb);
        for (int e = 0; e < NE; e++) dw_out[b*NE + e] = 0.f;
        dw_out[b*NE + i1] = wa;
        dw_out[b*NE + i2] = wb;
        g_eid[2*b] = i1; g_eid[2*b+1] = i2;
        g_wgt[2*b] = wa; g_wgt[2*b+1] = wb;
    }
}

// B-fragment loader, kq-plane layout: lane (pos=l31, half h) reads 16B at
// [kq][pc][h*8].  `in` is pre-offset by h*8.  Wave = 32pos x 32B contiguous.
__device__ __forceinline__ short8_t loadB32(
    const u16* __restrict__ in, int gn, int y, int xc, int tap, int kq)
{
    int dy = tap/3 - 1, dxk = tap - (tap/3)*3 - 1;
    int p = gn + dy*56 + dxk;
    bool vld = ((unsigned)(y + dy) < 56u) && ((unsigned)(xc + dxk) < 56u);
    int pc = p < 0 ? 0 : (p > 3135 ? 3135 : p);
    short8_t t = *(const short8_t*)(in + (size_t)kq*PLANE + pc*16);
    const short8_t zero = {};
    return vld ? t : zero;
}

// Single-shot A stage: both experts' mt-slice, 72KB = 4608 16B-units,
// 9 rounds of 512 threads. AL layout: [s36][es][h][m32][j8].
__device__ __forceinline__ void stageA(
    u16* AL, const u16* __restrict__ pw0, const u16* __restrict__ pw1,
    int mt, int tid)
{
    short8_t st[9];
    #pragma unroll
    for (int i = 0; i < 9; i++) {
        int u = i*512 + tid;
        int es = u >= 2304;
        int r = u - (es ? 2304 : 0);
        int s36 = r >> 6;
        int c = r & 63;
        st[i] = *(const short8_t*)((es ? pw1 : pw0) + s36*1024 + mt*512 + c*8);
    }
    #pragma unroll
    for (int i = 0; i < 9; i++) {
        int u = i*512 + tid;
        int es = u >= 2304;
        int r = u - (es ? 2304 : 0);
        int s36 = r >> 6;
        int c = r & 63;
        *(short8_t*)(AL + (s36*2 + es)*512 + c*8) = st[i];
    }
}

// ---------------- conv1 + bn1 + relu -> g_h ---------------------------------
// 1D grid 1664, XCD-chunked decode: L = (wg&7)*208 + wg/8; b = L/26,
// tile = (L%26)>>1, mt = L&1 -> (tile,mt) pairs adjacent on one XCD.
__global__ __launch_bounds__(512, 4) void conv1_kernel(const float* __restrict__ b1)
{
    __shared__ u16 AL[36864];           // 72KB, staged once
    int wg = blockIdx.x;
    int L  = (wg & 7) * (CGRID/8) + (wg >> 3);
    int b  = L / 26;
    int r  = L - b*26;
    int tile = r >> 1;
    int mt   = r & 1;
    int e0 = g_eid[2*b], e1 = g_eid[2*b+1];
    int tid = threadIdx.x;
    int lane = tid & 63, w = tid >> 6;  // 8 waves
    int es = w & 1, pg = w >> 1;        // expert slot (2), position group (4)
    int l31 = lane & 31, h = lane >> 5;
    int gn0 = tile*256 + pg*64 + l31;   // frag 0 position (may be >= 3136)
    int gn1 = gn0 + 32;                 // frag 1 position
    int y0 = gn0/56, xc0 = gn0 - y0*56;
    int y1 = gn1/56, xc1 = gn1 - y1*56;
    int e = es ? e1 : e0;
    const u16* in  = g_xb + (size_t)b*IMG_ + h*8;
    const u16* pw0 = g_pw1 + e0*PWSZ;
    const u16* pw1 = g_pw1 + e1*PWSZ;
    int aOff = es*512 + h*256 + l31*8;  // + s*1024

    floatx16 accA = {}, accB = {};      // frag 0 / frag 1 accumulators
    short8_t B0[BD], B1[BD];
    #pragma unroll
    for (int s = 0; s < BD; s++) {      // B prefetch issues FIRST (longest latency)
        B0[s] = loadB32(in, gn0, y0, xc0, s >> 2, s & 3);
        B1[s] = loadB32(in, gn1, y1, xc1, s >> 2, s & 3);
    }
    stageA(AL, pw0, pw1, mt, tid);
    __syncthreads();                    // the ONLY barrier

    short8_t Ar[3];                     // A register pipeline, depth 3
    #pragma unroll
    for (int i = 0; i < 3; i++)
        Ar[i] = *(const short8_t*)(AL + i*1024 + aOff);

    #pragma unroll
    for (int s = 0; s < 36; s++) {
        short8_t bb0 = B0[s % BD];      // capture BEFORE refill
        short8_t bb1 = B1[s % BD];
        int sp = s + BD;
        if (sp < 36) {                  // refill issues ahead of the MFMAs
            B0[s % BD] = loadB32(in, gn0, y0, xc0, sp >> 2, sp & 3);
            B1[s % BD] = loadB32(in, gn1, y1, xc1, sp >> 2, sp & 3);
        }
        short8_t a = Ar[s % 3];
        if (s + 3 < 36)                 // A refill 3 steps ahead (lgkmcnt cover)
            Ar[s % 3] = *(const short8_t*)(AL + (s+3)*1024 + aOff);
        accA = __builtin_amdgcn_mfma_f32_32x32x16_bf16(a, bb0, accA, 0, 0, 0);
        accB = __builtin_amdgcn_mfma_f32_32x32x16_bf16(a, bb1, accB, 0, 0, 0);
    }

    // epilogue -> g_h [kq][pos][ch16]: kq = mt*2 + (rg>>1), c = (rg&1)*8 + h*4
    u16* hb = g_h + (size_t)(2*b + es)*IMG_;
    #pragma unroll
    for (int f = 0; f < 2; f++) {
        int gn = f ? gn1 : gn0;
        if (gn < HW_) {
            #pragma unroll
            for (int rg = 0; rg < 4; rg++) {
                union { u16 u[4]; uint2 v; } t;
                #pragma unroll
                for (int rr = 0; rr < 4; rr++) {
                    int m = rg*8 + h*4 + rr;       // D row = (reg&3)+8*(reg>>2)+4*h
                    float v = (f ? accB : accA)[rg*4 + rr] + b1[e*64 + mt*32 + m];
                    t.u[rr] = f2b(fmaxf(v, 0.f));
                }
                int kq = mt*2 + (rg >> 1);
                *(uint2*)(hb + (size_t)kq*PLANE + (size_t)gn*16 + (rg & 1)*8 + h*4) = t.v;
            }
        }
    }
}

// ---------------- conv2 + bn2 + residual + cross-wave combine ---------------
__global__ __launch_bounds__(512, 4) void conv2_kernel(
    const float* __restrict__ x, const float* __restrict__ b2,
    float* __restrict__ out)
{
    __shared__ u16 AL[36864];           // 72KB; reused as 32KB f32 P after loop
    int wg = blockIdx.x;
    int L  = (wg & 7) * (CGRID/8) + (wg >> 3);
    int b  = L / 26;                    // SAME b->XCD map as conv1 (h L2 reuse)
    int r  = L - b*26;
    int tile = (NTILE-1) - (r >> 1);    // tile-LIFO within b (newest h first)
    int mt   = r & 1;
    int e0 = g_eid[2*b], e1 = g_eid[2*b+1];
    int tid = threadIdx.x;
    int lane = tid & 63, w = tid >> 6;
    int es = w & 1, pg = w >> 1;
    int l31 = lane & 31, h = lane >> 5;
    int gn0 = tile*256 + pg*64 + l31;
    int gn1 = gn0 + 32;
    int y0 = gn0/56, xc0 = gn0 - y0*56;
    int y1 = gn1/56, xc1 = gn1 - y1*56;
    int e = es ? e1 : e0;
    float wgt = g_wgt[2*b + es];
    const u16* in  = g_h + (size_t)(2*b + es)*IMG_ + h*8;  // own expert stream
    const u16* pw0 = g_pw2 + e0*PWSZ;
    const u16* pw1 = g_pw2 + e1*PWSZ;
    int aOff = es*512 + h*256 + l31*8;

    floatx16 accA = {}, accB = {};
    short8_t B0[BD], B1[BD];
    #pragma unroll
    for (int s = 0; s < BD; s++) {
        B0[s] = loadB32(in, gn0, y0, xc0, s >> 2, s & 3);
        B1[s] = loadB32(in, gn1, y1, xc1, s >> 2, s & 3);
    }
    stageA(AL, pw0, pw1, mt, tid);
    __syncthreads();

    short8_t Ar[3];
    #pragma unroll
    for (int i = 0; i < 3; i++)
        Ar[i] = *(const short8_t*)(AL + i*1024 + aOff);

    #pragma unroll
    for (int s = 0; s < 36; s++) {
        short8_t bb0 = B0[s % BD];      // capture BEFORE refill
        short8_t bb1 = B1[s % BD];
        int sp = s + BD;
        if (sp < 36) {
            B0[s % BD] = loadB32(in, gn0, y0, xc0, sp >> 2, sp & 3);
            B1[s % BD] = loadB32(in, gn1, y1, xc1, sp >> 2, sp & 3);
        }
        short8_t a = Ar[s % 3];
        if (s + 3 < 36)
            Ar[s % 3] = *(const short8_t*)(AL + (s+3)*1024 + aOff);
        accA = __builtin_amdgcn_mfma_f32_32x32x16_bf16(a, bb0, accA, 0, 0, 0);
        accB = __builtin_amdgcn_mfma_f32_32x32x16_bf16(a, bb1, accB, 0, 0, 0);
    }

    // combine: es0 waves drop w0*relu(y0+x) into LDS, es1 waves add+store.
    __syncthreads();                    // all waves done reading AL
    float* P = (float*)AL;              // [pg][f][m32][l31] f32 = 32KB
    const float* xb = x + (size_t)b*IMG_ + (size_t)(mt*32)*HW_;
    if (es == 0) {
        #pragma unroll
        for (int f = 0; f < 2; f++) {
            int gn = f ? gn1 : gn0;
            if (gn < HW_) {
                #pragma unroll
                for (int rg = 0; rg < 4; rg++)
                    #pragma unroll
                    for (int rr = 0; rr < 4; rr++) {
                        int m = rg*8 + h*4 + rr;
                        float v = (f ? accB : accA)[rg*4 + rr] + b2[e*64 + mt*32 + m]
                                  + xb[(size_t)m*HW_ + gn];
                        P[((pg*2 + f)*32 + m)*32 + l31] = wgt * fmaxf(v, 0.f);
                    }
            }
        }
    }
    __syncthreads();
    if (es == 1) {
        float* ob = out + (size_t)b*IMG_ + (size_t)(mt*32)*HW_;
        #pragma unroll
        for (int f = 0; f < 2; f++) {
            int gn = f ? gn1 : gn0;
            if (gn < HW_) {
                #pragma unroll
                for (int rg = 0; rg < 4; rg++)
                    #pragma unroll
                    for (int rr = 0; rr < 4; rr++) {
                        int m = rg*8 + h*4 + rr;
                        float v = (f ? accB : accA)[rg*4 + rr] + b2[e*64 + mt*32 + m]
                                  + xb[(size_t)m*HW_ + gn];
                        ob[(size_t)m*HW_ + gn] = wgt * fmaxf(v, 0.f)
                                                 + P[((pg*2 + f)*32 + m)*32 + l31];
                    }
            }
        }
    }
}

extern "C" void kernel_launch(void* const* d_in, const int* in_sizes, int n_in,
                              void* d_out, int out_size, void* d_ws, size_t ws_size,
                              hipStream_t stream) {
    const float* x   = (const float*)d_in[0];
    const float* gw  = (const float*)d_in[1];
    const float* gb  = (const float*)d_in[2];
    const float* w1  = (const float*)d_in[3];
    const float* s1  = (const float*)d_in[4];
    const float* b1  = (const float*)d_in[5];
    const float* w2  = (const float*)d_in[6];
    const float* s2  = (const float*)d_in[7];
    const float* b2  = (const float*)d_in[8];
    float* out = (float*)d_out;
    float* dw  = out + (size_t)BATCH * IMG_;   // dense_w region of d_out (f32)

    (void)d_ws; (void)ws_size;                 // zero d_ws usage (R1/R2 aborts)

    hipLaunchKernelGGL(pack_kernel, dim3(2304), dim3(256), 0, stream, w1, s1, w2, s2);
    hipLaunchKernelGGL(xconv_kernel, dim3(49, BATCH), dim3(256), 0, stream, x);
    hipLaunchKernelGGL(gate_fin_kernel, dim3(BATCH), dim3(64), 0, stream, gw, gb, dw);
    hipLaunchKernelGGL(conv1_kernel, dim3(CGRID), dim3(512), 0, stream, b1);
    hipLaunchKernelGGL(conv2_kernel, dim3(CGRID), dim3(512), 0, stream, x, b2, out);
}